// Round 3
// baseline (415.965 us; speedup 1.0000x reference)
//
#include <hip/hip_runtime.h>

typedef _Float16 half8  __attribute__((ext_vector_type(8)));
typedef _Float16 half2T __attribute__((ext_vector_type(2)));
typedef float    vfloat4 __attribute__((ext_vector_type(4)));

#define T_LEN 512
#define B_SZ  64
#define K_IN  868
#define KP    896            // 7 * 128, zero padded
#define E_DIM 100
#define M_TOT (T_LEN * B_SZ) // 32768, m = b*512 + t (b-major)

// ws layout (bytes)
#define WT_BYTES   (128 * KP * 2)          // 229376 : f16 Wt[128][896], [n][k]
#define BIAS_OFF   WT_BYTES                // f32 bias[128] (b_ih + b_hh, fwd|bwd)
#define XP_OFF     (BIAS_OFF + 512)        // f32 xp[32768][128]  ([b][t][128])
#define XP_BYTES   ((size_t)M_TOT * 128 * 4)
#define HS_OFF     (XP_OFF + XP_BYTES)     // f32 hs[32768][128]  ([b][t][128])

// ---------------------------------------------------------------- prep ----
__global__ __launch_bounds__(128) void prep_kernel(
    const float* __restrict__ Wf, const float* __restrict__ Wb,
    const float* __restrict__ bif, const float* __restrict__ bhf,
    const float* __restrict__ bib, const float* __restrict__ bhb,
    _Float16* __restrict__ Wt, float* __restrict__ bias)
{
    const int n = blockIdx.y;                       // 0..127 output channel
    const int k = blockIdx.x * 128 + threadIdx.x;   // 0..895
    float v = 0.f;
    if (k < K_IN) v = (n < 64) ? Wf[n * K_IN + k] : Wb[(n - 64) * K_IN + k];
    Wt[n * KP + k] = (_Float16)v;
    if (blockIdx.x == 0 && threadIdx.x == 0)
        bias[n] = (n < 64) ? (bif[n] + bhf[n]) : (bib[n - 64] + bhb[n - 64]);
}

// ---------------------------------------------------------------- GEMM ----
// xp[m][n] = sum_k x[m][k] * Wt[n][k] + bias[n]
__global__ __launch_bounds__(256) void gemm_kernel(
    const float* __restrict__ inputs, const int* __restrict__ pos,
    const float* __restrict__ emb, const _Float16* __restrict__ Wt,
    const float* __restrict__ bias, float* __restrict__ xp)
{
    __shared__ _Float16 Ah[128 * 128];   // [row=m][k], 16B blocks XOR-swizzled by row&7
    __shared__ _Float16 Bh[128 * 128];   // [row=n][k], same swizzle

    const int tid  = threadIdx.x;
    const int mb   = blockIdx.x;         // 0..255
    const int w    = tid >> 6;           // wave 0..3
    const int lane = tid & 63;
    const int q    = lane >> 4;          // quad 0..3
    const int lr   = lane & 15;
    const int wm   = w >> 1;             // 2x2 wave grid, each wave 64x64 of C
    const int wn   = w & 1;

    vfloat4 acc[4][4];
#pragma unroll
    for (int i = 0; i < 4; ++i)
#pragma unroll
        for (int j = 0; j < 4; ++j) { vfloat4 z = {0.f, 0.f, 0.f, 0.f}; acc[i][j] = z; }

    for (int kc = 0; kc < 7; ++kc) {
#pragma unroll
        for (int it = 0; it < 8; ++it) {
            const int bid = it * 256 + tid;
            const int row = bid >> 4;        // 0..127
            const int cb  = bid & 15;        // 16B k-block within chunk
            const int phys = row * 128 + ((cb ^ (row & 7)) << 3);

            half8 av;
            if (kc < 6) {
                const float4* src = (const float4*)(inputs + (size_t)(mb * 128 + row) * 768
                                                    + kc * 128 + cb * 8);
                float4 v0 = src[0], v1 = src[1];
                av[0] = (_Float16)v0.x; av[1] = (_Float16)v0.y;
                av[2] = (_Float16)v0.z; av[3] = (_Float16)v0.w;
                av[4] = (_Float16)v1.x; av[5] = (_Float16)v1.y;
                av[6] = (_Float16)v1.z; av[7] = (_Float16)v1.w;
            } else {
                const int m = mb * 128 + row;
                const int p = pos[m];
                const float* er = emb + (size_t)p * E_DIM;
                const int c0 = cb * 8;
#pragma unroll
                for (int e = 0; e < 8; ++e) {
                    const int c = c0 + e;
                    av[e] = (_Float16)((c < E_DIM) ? er[c] : 0.f);
                }
            }
            *(half8*)&Ah[phys] = av;

            half8 bv = *(const half8*)(Wt + (size_t)row * KP + kc * 128 + cb * 8);
            *(half8*)&Bh[phys] = bv;
        }
        __syncthreads();

#pragma unroll
        for (int s = 0; s < 4; ++s) {
            half8 af[4], bf[4];
            const int cbr = (s << 2) | q;
#pragma unroll
            for (int mt = 0; mt < 4; ++mt) {
                const int row = wm * 64 + mt * 16 + lr;
                af[mt] = *(const half8*)&Ah[row * 128 + ((cbr ^ (lr & 7)) << 3)];
            }
#pragma unroll
            for (int nt = 0; nt < 4; ++nt) {
                const int row = wn * 64 + nt * 16 + lr;
                bf[nt] = *(const half8*)&Bh[row * 128 + ((cbr ^ (lr & 7)) << 3)];
            }
#pragma unroll
            for (int mt = 0; mt < 4; ++mt)
#pragma unroll
                for (int nt = 0; nt < 4; ++nt)
                    acc[mt][nt] = __builtin_amdgcn_mfma_f32_16x16x32_f16(
                        af[mt], bf[nt], acc[mt][nt], 0, 0, 0);
        }
        __syncthreads();
    }

#pragma unroll
    for (int nt = 0; nt < 4; ++nt) {
        const int n = wn * 64 + nt * 16 + lr;
        const float bv = bias[n];
#pragma unroll
        for (int mt = 0; mt < 4; ++mt) {
#pragma unroll
            for (int r = 0; r < 4; ++r) {
                const int m = mb * 128 + wm * 64 + mt * 16 + q * 4 + r;
                xp[(size_t)m * 128 + n] = acc[mt][nt][r] + bv;
            }
        }
    }
}

// ---------------------------------------------------------------- scan ----
// one wave per (batch, direction). Recurrence chain per step kept minimal:
//   h -> mov_dpp(xor1, ~4cyc) -> cvt_pkrtz pack -> 32 readlane + 32 fdot2
//   -> reduce -> exp2 -> v_rcp -> h.   xp loads prefetched 8 steps ahead
//   (ring of 8 regs) so global latency (200-900cyc) stays OFF the chain.
__global__ __launch_bounds__(64) void scan_kernel(
    const float* __restrict__ Whf, const float* __restrict__ Whb,
    const float* __restrict__ xp, float* __restrict__ hs)
{
    const int b   = blockIdx.x;   // 0..63
    const int dir = blockIdx.y;   // 0 fwd, 1 bwd
    const int j   = threadIdx.x;  // 0..63 output unit
    const float* Wr = (dir ? Whb : Whf) + j * 64;

    half2T w2[32];
#pragma unroll
    for (int i = 0; i < 32; ++i) {
        w2[i][0] = (_Float16)Wr[2 * i];
        w2[i][1] = (_Float16)Wr[2 * i + 1];
    }

    const size_t base = (size_t)b * T_LEN * 128 + dir * 64 + j;
    const float* xpp = xp + base;
    float*       hsp = hs + base;

    const int rev = dir ? 1 : 0;

#define PF 8
    float xq[PF];
#pragma unroll
    for (int p = 0; p < PF; ++p) {
        const int t = rev ? (T_LEN - 1 - p) : p;
        xq[p] = xpp[(size_t)t * 128];
    }

    float h = 0.f;
    const float LOG2E2 = 2.885390081777927f;  // 2*log2(e)

    for (int it = 0; it < T_LEN; it += PF) {
#pragma unroll
        for (int u = 0; u < PF; ++u) {
            const int ii    = it + u;
            const int t_cur = rev ? (T_LEN - 1 - ii) : ii;
            const float xcur = xq[u];

            // prefetch PF steps ahead (clamped; duplicate tail loads harmless)
            int ipf = ii + PF; if (ipf > T_LEN - 1) ipf = T_LEN - 1;
            const int t_pf = rev ? (T_LEN - 1 - ipf) : ipf;
            xq[u] = xpp[(size_t)t_pf * 128];

            // broadcast h: neighbor via DPP quad_perm(1,0,3,2) == lane^1
            float hn;
#if __has_builtin(__builtin_amdgcn_mov_dpp)
            hn = __builtin_bit_cast(float,
                     __builtin_amdgcn_mov_dpp(__builtin_bit_cast(int, h),
                                              0xB1, 0xF, 0xF, false));
#else
            hn = __shfl_xor(h, 1, 64);
#endif
            // pack (h, hn) as f16x2; builtin returns __fp16x2 -> bit_cast to int
            int hpi;
#if __has_builtin(__builtin_amdgcn_cvt_pkrtz)
            hpi = __builtin_bit_cast(int, __builtin_amdgcn_cvt_pkrtz(h, hn));
#else
            { half2T hp; hp[0] = (_Float16)h; hp[1] = (_Float16)hn;
              hpi = __builtin_bit_cast(int, hp); }
#endif

            float d[4] = {0.f, 0.f, 0.f, 0.f};
#pragma unroll
            for (int i = 0; i < 32; ++i) {
                const int s = __builtin_amdgcn_readlane(hpi, 2 * i);
                d[i & 3] = __builtin_amdgcn_fdot2(__builtin_bit_cast(half2T, s),
                                                  w2[i], d[i & 3], false);
            }

            const float z = xcur + ((d[0] + d[1]) + (d[2] + d[3]));
            // tanh(z) = 1 - 2/(1+exp(2z)); exp(2z)=2^(z*2log2e); rcp approx ok
#if __has_builtin(__builtin_amdgcn_exp2f)
            const float e = __builtin_amdgcn_exp2f(z * LOG2E2);
#else
            const float e = exp2f(z * LOG2E2);
#endif
#if __has_builtin(__builtin_amdgcn_rcpf)
            const float r = __builtin_amdgcn_rcpf(1.f + e);
#else
            const float r = 1.f / (1.f + e);
#endif
            h = __builtin_fmaf(-2.f, r, 1.f);

            hsp[(size_t)t_cur * 128] = h;
        }
    }
#undef PF
}

// ---------------------------------------------------------------- head ----
__global__ __launch_bounds__(64) void head_kernel(
    const float* __restrict__ hs, const float* __restrict__ W1,
    const float* __restrict__ b1, const float* __restrict__ gamma,
    const float* __restrict__ beta, const float* __restrict__ W2,
    const float* __restrict__ b2, float* __restrict__ out)
{
    const int r = blockIdx.x * 64 + threadIdx.x;   // 0..32767 (= b*512+t)
    const float4* x = (const float4*)(hs + (size_t)r * 128);
    float4 xv[32];
#pragma unroll
    for (int i = 0; i < 32; ++i) xv[i] = x[i];

    float h1[32];
    for (int jj = 0; jj < 32; ++jj) {
        const float4* wrow = (const float4*)(W1 + jj * 128);  // uniform -> scalar loads
        float a = 0.f;
#pragma unroll
        for (int k = 0; k < 32; ++k) {
            const float4 wv = wrow[k];
            a += wv.x * xv[k].x + wv.y * xv[k].y + wv.z * xv[k].z + wv.w * xv[k].w;
        }
        h1[jj] = a + b1[jj];
    }

    float mu = 0.f;
#pragma unroll
    for (int jj = 0; jj < 32; ++jj) mu += h1[jj];
    mu *= (1.f / 32.f);
    float var = 0.f;
#pragma unroll
    for (int jj = 0; jj < 32; ++jj) { const float dlt = h1[jj] - mu; var += dlt * dlt; }
    var *= (1.f / 32.f);
    const float rstd = rsqrtf(var + 1e-5f);

    float y[32];
#pragma unroll
    for (int jj = 0; jj < 32; ++jj) {
        const float v = (h1[jj] - mu) * rstd * gamma[jj] + beta[jj];
        y[jj] = v > 0.f ? v : 0.f;
    }

    float oc[4];
#pragma unroll
    for (int c = 0; c < 4; ++c) {
        float a = b2[c];
#pragma unroll
        for (int jj = 0; jj < 32; ++jj) a += W2[c * 32 + jj] * y[jj];
        oc[c] = a;
    }
    float4 o; o.x = oc[0]; o.y = oc[1]; o.z = oc[2]; o.w = oc[3];
    *(float4*)(out + (size_t)r * 4) = o;
}

// -------------------------------------------------------------- launch ----
extern "C" void kernel_launch(void* const* d_in, const int* in_sizes, int n_in,
                              void* d_out, int out_size, void* d_ws, size_t ws_size,
                              hipStream_t stream)
{
    const float* inputs = (const float*)d_in[0];
    const int*   pos    = (const int*)d_in[1];
    const float* emb    = (const float*)d_in[2];
    const float* Wihf   = (const float*)d_in[3];
    const float* Whhf   = (const float*)d_in[4];
    const float* bihf   = (const float*)d_in[5];
    const float* bhhf   = (const float*)d_in[6];
    const float* Wihb   = (const float*)d_in[7];
    const float* Whhb   = (const float*)d_in[8];
    const float* bihb   = (const float*)d_in[9];
    const float* bhhb   = (const float*)d_in[10];
    const float* W1     = (const float*)d_in[11];
    const float* b1v    = (const float*)d_in[12];
    const float* gam    = (const float*)d_in[13];
    const float* bet    = (const float*)d_in[14];
    const float* W2     = (const float*)d_in[15];
    const float* b2v    = (const float*)d_in[16];

    char* ws = (char*)d_ws;
    _Float16* Wt  = (_Float16*)(ws);
    float* bias   = (float*)(ws + BIAS_OFF);
    float* xp     = (float*)(ws + XP_OFF);
    float* hsbuf  = (float*)(ws + HS_OFF);

    prep_kernel<<<dim3(7, 128), 128, 0, stream>>>(Wihf, Wihb, bihf, bhhf, bihb, bhhb, Wt, bias);
    gemm_kernel<<<dim3(256), 256, 0, stream>>>(inputs, pos, emb, Wt, bias, xp);
    scan_kernel<<<dim3(64, 2), 64, 0, stream>>>(Whhf, Whhb, xp, hsbuf);
    head_kernel<<<dim3(512), 64, 0, stream>>>(hsbuf, W1, b1v, gam, bet, W2, b2v, (float*)d_out);
}

// Round 4
// 369.732 us; speedup vs baseline: 1.1250x; 1.1250x over previous
//
#include <hip/hip_runtime.h>

typedef _Float16 half8  __attribute__((ext_vector_type(8)));
typedef _Float16 half2T __attribute__((ext_vector_type(2)));
typedef float    vfloat4 __attribute__((ext_vector_type(4)));

#define T_LEN 512
#define B_SZ  64
#define K_IN  868
#define KP    896            // 7 * 128, zero padded
#define E_DIM 100
#define M_TOT (T_LEN * B_SZ) // 32768, m = b*512 + t (b-major)

// ws layout (bytes)
#define WT_BYTES   (128 * KP * 2)          // 229376 : f16 Wt[128][896], [n][k]
#define BIAS_OFF   WT_BYTES                // f32 bias[128] (b_ih + b_hh, fwd|bwd)
#define XP_OFF     (BIAS_OFF + 512)        // f32 xp[32768][128]  ([b][t][128])
#define XP_BYTES   ((size_t)M_TOT * 128 * 4)
#define HS_OFF     (XP_OFF + XP_BYTES)     // f32 hs[32768][128]  ([b][t][128])

// ---------------------------------------------------------------- prep ----
__global__ __launch_bounds__(128) void prep_kernel(
    const float* __restrict__ Wf, const float* __restrict__ Wb,
    const float* __restrict__ bif, const float* __restrict__ bhf,
    const float* __restrict__ bib, const float* __restrict__ bhb,
    _Float16* __restrict__ Wt, float* __restrict__ bias)
{
    const int n = blockIdx.y;                       // 0..127 output channel
    const int k = blockIdx.x * 128 + threadIdx.x;   // 0..895
    float v = 0.f;
    if (k < K_IN) v = (n < 64) ? Wf[n * K_IN + k] : Wb[(n - 64) * K_IN + k];
    Wt[n * KP + k] = (_Float16)v;
    if (blockIdx.x == 0 && threadIdx.x == 0)
        bias[n] = (n < 64) ? (bif[n] + bhf[n]) : (bib[n - 64] + bhb[n - 64]);
}

// ---------------------------------------------------------------- GEMM ----
// xp[m][n] = sum_k x[m][k] * Wt[n][k] + bias[n]
__global__ __launch_bounds__(256) void gemm_kernel(
    const float* __restrict__ inputs, const int* __restrict__ pos,
    const float* __restrict__ emb, const _Float16* __restrict__ Wt,
    const float* __restrict__ bias, float* __restrict__ xp)
{
    __shared__ _Float16 Ah[128 * 128];   // [row=m][k], 16B blocks XOR-swizzled by row&7
    __shared__ _Float16 Bh[128 * 128];   // [row=n][k], same swizzle

    const int tid  = threadIdx.x;
    const int mb   = blockIdx.x;         // 0..255
    const int w    = tid >> 6;           // wave 0..3
    const int lane = tid & 63;
    const int q    = lane >> 4;          // quad 0..3
    const int lr   = lane & 15;
    const int wm   = w >> 1;             // 2x2 wave grid, each wave 64x64 of C
    const int wn   = w & 1;

    vfloat4 acc[4][4];
#pragma unroll
    for (int i = 0; i < 4; ++i)
#pragma unroll
        for (int j = 0; j < 4; ++j) { vfloat4 z = {0.f, 0.f, 0.f, 0.f}; acc[i][j] = z; }

    for (int kc = 0; kc < 7; ++kc) {
#pragma unroll
        for (int it = 0; it < 8; ++it) {
            const int bid = it * 256 + tid;
            const int row = bid >> 4;        // 0..127
            const int cb  = bid & 15;        // 16B k-block within chunk
            const int phys = row * 128 + ((cb ^ (row & 7)) << 3);

            half8 av;
            if (kc < 6) {
                const float4* src = (const float4*)(inputs + (size_t)(mb * 128 + row) * 768
                                                    + kc * 128 + cb * 8);
                float4 v0 = src[0], v1 = src[1];
                av[0] = (_Float16)v0.x; av[1] = (_Float16)v0.y;
                av[2] = (_Float16)v0.z; av[3] = (_Float16)v0.w;
                av[4] = (_Float16)v1.x; av[5] = (_Float16)v1.y;
                av[6] = (_Float16)v1.z; av[7] = (_Float16)v1.w;
            } else {
                const int m = mb * 128 + row;
                const int p = pos[m];
                const float* er = emb + (size_t)p * E_DIM;
                const int c0 = cb * 8;
#pragma unroll
                for (int e = 0; e < 8; ++e) {
                    const int c = c0 + e;
                    av[e] = (_Float16)((c < E_DIM) ? er[c] : 0.f);
                }
            }
            *(half8*)&Ah[phys] = av;

            half8 bv = *(const half8*)(Wt + (size_t)row * KP + kc * 128 + cb * 8);
            *(half8*)&Bh[phys] = bv;
        }
        __syncthreads();

#pragma unroll
        for (int s = 0; s < 4; ++s) {
            half8 af[4], bf[4];
            const int cbr = (s << 2) | q;
#pragma unroll
            for (int mt = 0; mt < 4; ++mt) {
                const int row = wm * 64 + mt * 16 + lr;
                af[mt] = *(const half8*)&Ah[row * 128 + ((cbr ^ (lr & 7)) << 3)];
            }
#pragma unroll
            for (int nt = 0; nt < 4; ++nt) {
                const int row = wn * 64 + nt * 16 + lr;
                bf[nt] = *(const half8*)&Bh[row * 128 + ((cbr ^ (lr & 7)) << 3)];
            }
#pragma unroll
            for (int mt = 0; mt < 4; ++mt)
#pragma unroll
                for (int nt = 0; nt < 4; ++nt)
                    acc[mt][nt] = __builtin_amdgcn_mfma_f32_16x16x32_f16(
                        af[mt], bf[nt], acc[mt][nt], 0, 0, 0);
        }
        __syncthreads();
    }

#pragma unroll
    for (int nt = 0; nt < 4; ++nt) {
        const int n = wn * 64 + nt * 16 + lr;
        const float bv = bias[n];
#pragma unroll
        for (int mt = 0; mt < 4; ++mt) {
#pragma unroll
            for (int r = 0; r < 4; ++r) {
                const int m = mb * 128 + wm * 64 + mt * 16 + q * 4 + r;
                xp[(size_t)m * 128 + n] = acc[mt][nt][r] + bv;
            }
        }
    }
}

// ---------------------------------------------------------------- scan ----
// R1 loop structure EXACTLY (prefetch depth 1, simple loop — PF=8 unroll
// regressed in R3). Only two changes vs R1, both pure chain-cycle removals:
//   (a) neighbor via mov_dpp quad_perm(1,0,3,2) instead of ds_swizzle (~116cy)
//   (b) tanh via exp2+rcp instead of __expf + full-precision divide (~40cy)
__global__ __launch_bounds__(64) void scan_kernel(
    const float* __restrict__ Whf, const float* __restrict__ Whb,
    const float* __restrict__ xp, float* __restrict__ hs)
{
    const int b   = blockIdx.x;   // 0..63
    const int dir = blockIdx.y;   // 0 fwd, 1 bwd
    const int j   = threadIdx.x;  // 0..63 output unit
    const float* Wr = (dir ? Whb : Whf) + j * 64;

    half2T w2[32];
#pragma unroll
    for (int i = 0; i < 32; ++i) {
        w2[i][0] = (_Float16)Wr[2 * i];
        w2[i][1] = (_Float16)Wr[2 * i + 1];
    }

    const size_t base = (size_t)b * T_LEN * 128 + dir * 64 + j;
    const float* xpp = xp + base;
    float*       hsp = hs + base;

    int tt = dir ? (T_LEN - 1) : 0;
    const int stp = dir ? -1 : 1;
    float xcur = xpp[(size_t)tt * 128];
    float h = 0.f;
    const float LOG2E2 = 2.885390081777927f;  // 2*log2(e)

    for (int it = 0; it < T_LEN; ++it) {
        const int tn = tt + stp;
        const int tc = tn < 0 ? 0 : (tn > T_LEN - 1 ? T_LEN - 1 : tn);
        const float xnext = xpp[(size_t)tc * 128];

        // (a) neighbor h via DPP quad_perm [1,0,3,2] == lane^1
        const float hn = __builtin_bit_cast(float,
                 __builtin_amdgcn_mov_dpp(__builtin_bit_cast(int, h),
                                          0xB1, 0xF, 0xF, false));
        const int hpi = __builtin_bit_cast(int, __builtin_amdgcn_cvt_pkrtz(h, hn));

        float d[4] = {0.f, 0.f, 0.f, 0.f};
#pragma unroll
        for (int i = 0; i < 32; ++i) {
            const int s = __builtin_amdgcn_readlane(hpi, 2 * i);
            d[i & 3] = __builtin_amdgcn_fdot2(__builtin_bit_cast(half2T, s),
                                              w2[i], d[i & 3], false);
        }

        const float z = xcur + ((d[0] + d[1]) + (d[2] + d[3]));
        // (b) tanh(z) = 1 - 2/(1+exp(2z)); exp via exp2, divide via v_rcp
        const float e = __builtin_amdgcn_exp2f(z * LOG2E2);
        const float r = __builtin_amdgcn_rcpf(1.f + e);
        h = __builtin_fmaf(-2.f, r, 1.f);

        hsp[(size_t)tt * 128] = h;
        xcur = xnext;
        tt = tn;
    }
}

// ---------------------------------------------------------------- head ----
// 4 threads per row (k-split 128 = 4 x 32), W1 staged in LDS once per block.
// Thread t: row = blk*64 + t>>2, kg = t&3, owns k-chunks {16c + 4*kg .. +3}.
// LDS reads: same-row lanes broadcast; kg stride = 4 words -> distinct banks.
// Quad all-reduce of partials via DPP quad_perm butterflies; lane kg writes
// output channel kg (coalesced).
__global__ __launch_bounds__(256) void head_kernel(
    const float* __restrict__ hs, const float* __restrict__ W1,
    const float* __restrict__ b1, const float* __restrict__ gamma,
    const float* __restrict__ beta, const float* __restrict__ W2,
    const float* __restrict__ b2, float* __restrict__ out)
{
    __shared__ float4 sW1[32 * 32];            // W1[32][128] as float4
    __shared__ float  sb1[32], sg[32], sbt[32], sW2[4 * 34], sb2[4];

    const int t = threadIdx.x;
    const float4* W1v = (const float4*)W1;
    for (int i = t; i < 1024; i += 256) sW1[i] = W1v[i];
    if (t < 32) { sb1[t] = b1[t]; sg[t] = gamma[t]; sbt[t] = beta[t]; }
    if (t < 128) sW2[(t >> 5) * 34 + (t & 31)] = W2[t];
    if (t < 4)  sb2[t] = b2[t];
    __syncthreads();

    const int m  = blockIdx.x * 64 + (t >> 2);
    const int kg = t & 3;

    const float4* xrow = (const float4*)(hs + (size_t)m * 128);
    float4 xq[8];
#pragma unroll
    for (int c = 0; c < 8; ++c) xq[c] = xrow[c * 4 + kg];

    float h1[32];
#pragma unroll
    for (int jj = 0; jj < 32; ++jj) {
        float a = 0.f;
#pragma unroll
        for (int c = 0; c < 8; ++c) {
            const float4 wv = sW1[jj * 32 + c * 4 + kg];
            a += wv.x * xq[c].x + wv.y * xq[c].y + wv.z * xq[c].z + wv.w * xq[c].w;
        }
        // quad all-reduce: xor1 then xor2 (quad_perm [1,0,3,2], [2,3,0,1])
        a += __builtin_bit_cast(float,
             __builtin_amdgcn_mov_dpp(__builtin_bit_cast(int, a), 0xB1, 0xF, 0xF, false));
        a += __builtin_bit_cast(float,
             __builtin_amdgcn_mov_dpp(__builtin_bit_cast(int, a), 0x4E, 0xF, 0xF, false));
        h1[jj] = a + sb1[jj];
    }

    float mu = 0.f;
#pragma unroll
    for (int jj = 0; jj < 32; ++jj) mu += h1[jj];
    mu *= (1.f / 32.f);
    float var = 0.f;
#pragma unroll
    for (int jj = 0; jj < 32; ++jj) { const float dlt = h1[jj] - mu; var += dlt * dlt; }
    var *= (1.f / 32.f);
    const float rstd = rsqrtf(var + 1e-5f);

    float acc2 = sb2[kg];
#pragma unroll
    for (int jj = 0; jj < 32; ++jj) {
        const float v = (h1[jj] - mu) * rstd * sg[jj] + sbt[jj];
        const float y = v > 0.f ? v : 0.f;
        acc2 += sW2[kg * 34 + jj] * y;
    }
    out[(size_t)m * 4 + kg] = acc2;
}

// -------------------------------------------------------------- launch ----
extern "C" void kernel_launch(void* const* d_in, const int* in_sizes, int n_in,
                              void* d_out, int out_size, void* d_ws, size_t ws_size,
                              hipStream_t stream)
{
    const float* inputs = (const float*)d_in[0];
    const int*   pos    = (const int*)d_in[1];
    const float* emb    = (const float*)d_in[2];
    const float* Wihf   = (const float*)d_in[3];
    const float* Whhf   = (const float*)d_in[4];
    const float* bihf   = (const float*)d_in[5];
    const float* bhhf   = (const float*)d_in[6];
    const float* Wihb   = (const float*)d_in[7];
    const float* Whhb   = (const float*)d_in[8];
    const float* bihb   = (const float*)d_in[9];
    const float* bhhb   = (const float*)d_in[10];
    const float* W1     = (const float*)d_in[11];
    const float* b1v    = (const float*)d_in[12];
    const float* gam    = (const float*)d_in[13];
    const float* bet    = (const float*)d_in[14];
    const float* W2     = (const float*)d_in[15];
    const float* b2v    = (const float*)d_in[16];

    char* ws = (char*)d_ws;
    _Float16* Wt  = (_Float16*)(ws);
    float* bias   = (float*)(ws + BIAS_OFF);
    float* xp     = (float*)(ws + XP_OFF);
    float* hsbuf  = (float*)(ws + HS_OFF);

    prep_kernel<<<dim3(7, 128), 128, 0, stream>>>(Wihf, Wihb, bihf, bhhf, bihb, bhhb, Wt, bias);
    gemm_kernel<<<dim3(256), 256, 0, stream>>>(inputs, pos, emb, Wt, bias, xp);
    scan_kernel<<<dim3(64, 2), 64, 0, stream>>>(Whhf, Whhb, xp, hsbuf);
    head_kernel<<<dim3(512), 256, 0, stream>>>(hsbuf, W1, b1v, gam, bet, W2, b2v, (float*)d_out);
}